// Round 9
// baseline (120.156 us; speedup 1.0000x reference)
//
#include <hip/hip_runtime.h>
#include <math.h>

typedef __attribute__((ext_vector_type(8))) short bf16x8;
typedef __attribute__((ext_vector_type(4))) float f32x4;

#define MFMA __builtin_amdgcn_mfma_f32_16x16x32_bf16
#define SWZ512(row) ((((unsigned)(row)) & 7u) << 4)

static __device__ __forceinline__ unsigned short f2bf(float f) {
  union { float f; unsigned u; } a; a.f = f;
  unsigned u = a.u;
  unsigned r = u + 0x7FFF + ((u >> 16) & 1);   // RNE
  return (unsigned short)(r >> 16);
}
static __device__ __forceinline__ float bf2f(unsigned short h) {
  union { unsigned u; float f; } a; a.u = ((unsigned)h) << 16;
  return a.f;
}
static __device__ __forceinline__ float tanh_fast(float x) {
  float ax = fabsf(x);
  float e = __expf(-2.0f * ax);
  float t = (1.0f - e) / (1.0f + e);
  t = (ax > 10.0f) ? 1.0f : t;
  return (x < 0.0f) ? -t : t;
}

// Weight transpose+split (verified r6-r8 code).
__global__ __launch_bounds__(256) void k_split(
    const float* __restrict__ W1, const float* __restrict__ W2, const float* __restrict__ Wv,
    unsigned short* __restrict__ W1Th, unsigned short* __restrict__ W1Tl,
    unsigned short* __restrict__ W2Th, unsigned short* __restrict__ W2Tl,
    unsigned short* __restrict__ WvTh, unsigned short* __restrict__ WvTl)
{
  const int b = blockIdx.x, t = threadIdx.x;
  __shared__ unsigned short shh[64 * 72], shl[64 * 72];
  const float* W; unsigned short *Th, *Tl; int Kd, Nd, k0, n0;
  if (b < 64)       { W = W1; Th = W1Th; Tl = W1Tl; Kd = 256;  Nd = 1024; k0 = (b & 3) * 64;         n0 = (b >> 2) * 64; }
  else if (b < 128) { W = W2; Th = W2Th; Tl = W2Tl; Kd = 1024; Nd = 256;  k0 = ((b - 64) & 15) * 64; n0 = ((b - 64) >> 4) * 64; }
  else              { W = Wv; Th = WvTh; Tl = WvTl; Kd = 256;  Nd = 256;  k0 = ((b - 128) & 3) * 64; n0 = ((b - 128) >> 2) * 64; }

  const int kloc = t >> 4, n4 = t & 15;
#pragma unroll
  for (int p = 0; p < 4; ++p) {
    const int kk = p * 16 + kloc;
    const float4 v = *reinterpret_cast<const float4*>(&W[(size_t)(k0 + kk) * Nd + n0 + n4 * 4]);
    const float vv[4] = {v.x, v.y, v.z, v.w};
#pragma unroll
    for (int e = 0; e < 4; ++e) {
      const unsigned short hh = f2bf(vv[e]);
      shh[(n4 * 4 + e) * 72 + kk] = hh;
      shl[(n4 * 4 + e) * 72 + kk] = f2bf(vv[e] - bf2f(hh));
    }
  }
  __syncthreads();
  const int nl = t >> 2, ko = (t & 3) * 16;
  const size_t dst = (size_t)(n0 + nl) * Kd + k0 + ko;
  *reinterpret_cast<uint4*>(&Th[dst])     = *reinterpret_cast<const uint4*>(&shh[nl * 72 + ko]);
  *reinterpret_cast<uint4*>(&Th[dst + 8]) = *reinterpret_cast<const uint4*>(&shh[nl * 72 + ko + 8]);
  *reinterpret_cast<uint4*>(&Tl[dst])     = *reinterpret_cast<const uint4*>(&shl[nl * 72 + ko]);
  *reinterpret_cast<uint4*>(&Tl[dst + 8]) = *reinterpret_cast<const uint4*>(&shl[nl * 72 + ko + 8]);
}

// LDS map (bytes):
//   0      XH [32][512B swz]   16384  XL
//   32768  FH                  49152  FL
//   65536  HC buf0: H 4K | L 4K ; 73728 HC buf1: H 4K | L 4K
//   81920  PX [32][16] f32 (2K); 83968 PF (2K); 86016 ALS (128B)
__global__ __launch_bounds__(1024, 4) void k_fused(
    const float* __restrict__ X, const float* __restrict__ pb1, const float* __restrict__ pb2,
    const unsigned short* __restrict__ W1Th, const unsigned short* __restrict__ W1Tl,
    const unsigned short* __restrict__ W2Th, const unsigned short* __restrict__ W2Tl,
    const unsigned short* __restrict__ WvTh, const unsigned short* __restrict__ WvTl,
    float* __restrict__ OUT)
{
  __shared__ __align__(16) unsigned char smem[86272];
  const int t = threadIdx.x;
  const int l = t & 63, w = t >> 6;      // 16 waves
  const int cl = l & 15, g = l >> 4;
  const int r0 = blockIdx.x * 32;
  const int i1 = w & 1, j1 = w >> 1;     // g1 (w<8): frag rows i1*16, cols j1*16 of Hc[32][64]
  const int u  = w - 8;                  // g2 (w>=8): output cols u*32..u*32+31

  // ---- prologue: stage X -> XH/XL planes (once) ----
  {
    const int row = t >> 5, sl = t & 31;
    const float* src = &X[(size_t)(r0 + row) * 256 + sl * 8];
    const float4 v0 = *reinterpret_cast<const float4*>(src);
    const float4 v1 = *reinterpret_cast<const float4*>(src + 4);
    const float vv[8] = {v0.x, v0.y, v0.z, v0.w, v1.x, v1.y, v1.z, v1.w};
    union { bf16x8 v; unsigned short s[8]; } uh, ul;
#pragma unroll
    for (int e = 0; e < 8; ++e) {
      uh.s[e] = f2bf(vv[e]);
      ul.s[e] = f2bf(vv[e] - bf2f(uh.s[e]));
    }
    const unsigned byte = row * 512 + (((unsigned)(sl * 16)) ^ SWZ512(row));
    *reinterpret_cast<bf16x8*>(smem + byte) = uh.v;
    *reinterpret_cast<bf16x8*>(smem + 16384 + byte) = ul.v;
  }
  __syncthreads();

  f32x4 oacc[2][2] = {};   // g2 accumulators

  // ---- main loop: 16 chunks of 64 H-cols, 1 barrier each ----
  for (int cc = 0; cc <= 16; ++cc) {
    if (w < 8 && cc < 16) {
      const int hcol = j1 * 16 + cl;            // col within chunk
      const int wrow = cc * 64 + hcol;          // W1T row
      const float b1v = pb1[wrow];
      const int arow = i1 * 16 + cl;
      f32x4 hA = {}, hB = {};
#pragma unroll
      for (int ks = 0; ks < 8; ks += 2) {
        const bf16x8 bh0 = *reinterpret_cast<const bf16x8*>(&W1Th[(size_t)wrow * 256 + ks * 32 + g * 8]);
        const bf16x8 bl0 = *reinterpret_cast<const bf16x8*>(&W1Tl[(size_t)wrow * 256 + ks * 32 + g * 8]);
        const bf16x8 bh1 = *reinterpret_cast<const bf16x8*>(&W1Th[(size_t)wrow * 256 + (ks + 1) * 32 + g * 8]);
        const bf16x8 bl1 = *reinterpret_cast<const bf16x8*>(&W1Tl[(size_t)wrow * 256 + (ks + 1) * 32 + g * 8]);
        const unsigned o0 = (unsigned)(ks * 64 + g * 16) ^ SWZ512(arow);
        const unsigned o1 = (unsigned)((ks + 1) * 64 + g * 16) ^ SWZ512(arow);
        const bf16x8 xh0 = *reinterpret_cast<const bf16x8*>(smem + arow * 512 + o0);
        const bf16x8 xl0 = *reinterpret_cast<const bf16x8*>(smem + 16384 + arow * 512 + o0);
        const bf16x8 xh1 = *reinterpret_cast<const bf16x8*>(smem + arow * 512 + o1);
        const bf16x8 xl1 = *reinterpret_cast<const bf16x8*>(smem + 16384 + arow * 512 + o1);
        hA = MFMA(xh0, bh0, hA, 0, 0, 0);
        hA = MFMA(xh0, bl0, hA, 0, 0, 0);
        hA = MFMA(xl0, bh0, hA, 0, 0, 0);
        hB = MFMA(xh1, bh1, hB, 0, 0, 0);
        hB = MFMA(xh1, bl1, hB, 0, 0, 0);
        hB = MFMA(xl1, bh1, hB, 0, 0, 0);
      }
      unsigned char* HC = smem + 65536 + (cc & 1) * 8192;
#pragma unroll
      for (int r = 0; r < 4; ++r) {
        const int samp = i1 * 16 + g * 4 + r;
        const float hv = tanh_fast(hA[r] + hB[r] + b1v);
        const unsigned short hh = f2bf(hv);
        const unsigned byte = samp * 128 + (((unsigned)(hcol * 2)) ^ ((((unsigned)samp) & 7u) << 4));
        *reinterpret_cast<unsigned short*>(HC + byte) = hh;
        *reinterpret_cast<unsigned short*>(HC + 4096 + byte) = f2bf(hv - bf2f(hh));
      }
    }

    if (w >= 8 && cc >= 1) {
      const int c2 = cc - 1;
      const unsigned char* HC = smem + 65536 + (c2 & 1) * 8192;
      bf16x8 b2h[2][2], b2l[2][2], a2h[2][2], a2l[2][2];
#pragma unroll
      for (int j = 0; j < 2; ++j)
#pragma unroll
        for (int ks = 0; ks < 2; ++ks) {
          const size_t off = (size_t)(u * 32 + j * 16 + cl) * 1024 + c2 * 64 + ks * 32 + g * 8;
          b2h[j][ks] = *reinterpret_cast<const bf16x8*>(&W2Th[off]);
          b2l[j][ks] = *reinterpret_cast<const bf16x8*>(&W2Tl[off]);
        }
#pragma unroll
      for (int i = 0; i < 2; ++i)
#pragma unroll
        for (int ks = 0; ks < 2; ++ks) {
          const int row = i * 16 + cl;
          const unsigned byte = row * 128 + (((unsigned)(ks * 64 + g * 16)) ^ ((((unsigned)row) & 7u) << 4));
          a2h[i][ks] = *reinterpret_cast<const bf16x8*>(HC + byte);
          a2l[i][ks] = *reinterpret_cast<const bf16x8*>(HC + 4096 + byte);
        }
#pragma unroll
      for (int i = 0; i < 2; ++i)
#pragma unroll
        for (int j = 0; j < 2; ++j)
#pragma unroll
          for (int ks = 0; ks < 2; ++ks) {
            oacc[i][j] = MFMA(a2h[i][ks], b2h[j][ks], oacc[i][j], 0, 0, 0);
            oacc[i][j] = MFMA(a2h[i][ks], b2l[j][ks], oacc[i][j], 0, 0, 0);
            oacc[i][j] = MFMA(a2l[i][ks], b2h[j][ks], oacc[i][j], 0, 0, 0);
          }
    }
    __syncthreads();
  }

  // ---- epilogue (g2): f = oacc + b2 + x ; write F planes; keep f in oacc ----
  if (w >= 8) {
    float b2v[2];
#pragma unroll
    for (int j = 0; j < 2; ++j) b2v[j] = pb2[u * 32 + j * 16 + cl];
#pragma unroll
    for (int i = 0; i < 2; ++i)
#pragma unroll
      for (int j = 0; j < 2; ++j)
#pragma unroll
        for (int r = 0; r < 4; ++r) {
          const int row = i * 16 + g * 4 + r;
          const int col = u * 32 + j * 16 + cl;
          const float xv = X[(size_t)(r0 + row) * 256 + col];
          const float f = oacc[i][j][r] + b2v[j] + xv;
          oacc[i][j][r] = f;
          const unsigned short fh = f2bf(f);
          const unsigned byte = row * 512 + (((unsigned)(col * 2)) ^ SWZ512(row));
          *reinterpret_cast<unsigned short*>(smem + 32768 + byte) = fh;
          *reinterpret_cast<unsigned short*>(smem + 49152 + byte) = f2bf(f - bf2f(fh));
        }
  }
  __syncthreads();

  // ---- V phase (all 16 waves): wave owns Wv cols w*16..w*16+15 ----
  {
    bf16x8 wvh[8], wvl[8];
#pragma unroll
    for (int ks = 0; ks < 8; ++ks) {
      const size_t off = (size_t)(w * 16 + cl) * 256 + ks * 32 + g * 8;
      wvh[ks] = *reinterpret_cast<const bf16x8*>(&WvTh[off]);
      wvl[ks] = *reinterpret_cast<const bf16x8*>(&WvTl[off]);
    }
    float vx_[2][4] = {}, vf_[2][4] = {};
#pragma unroll
    for (int i = 0; i < 2; ++i) {
      f32x4 zx = {}, zf = {};
#pragma unroll
      for (int ks = 0; ks < 8; ++ks) {
        const int row = i * 16 + cl;
        const unsigned o = (unsigned)(ks * 64 + g * 16) ^ SWZ512(row);
        const bf16x8 xhv = *reinterpret_cast<const bf16x8*>(smem + row * 512 + o);
        const bf16x8 xlv = *reinterpret_cast<const bf16x8*>(smem + 16384 + row * 512 + o);
        const bf16x8 fhv = *reinterpret_cast<const bf16x8*>(smem + 32768 + row * 512 + o);
        const bf16x8 flv = *reinterpret_cast<const bf16x8*>(smem + 49152 + row * 512 + o);
        zx = MFMA(xhv, wvh[ks], zx, 0, 0, 0);
        zx = MFMA(xhv, wvl[ks], zx, 0, 0, 0);
        zx = MFMA(xlv, wvh[ks], zx, 0, 0, 0);
        zf = MFMA(fhv, wvh[ks], zf, 0, 0, 0);
        zf = MFMA(fhv, wvl[ks], zf, 0, 0, 0);
        zf = MFMA(flv, wvh[ks], zf, 0, 0, 0);
      }
#pragma unroll
      for (int r = 0; r < 4; ++r) {
        vx_[i][r] = fmaf(zx[r], zx[r], vx_[i][r]);
        vf_[i][r] = fmaf(zf[r], zf[r], vf_[i][r]);
      }
    }
    float* PX = (float*)(smem + 81920);
    float* PF = (float*)(smem + 83968);
#pragma unroll
    for (int i = 0; i < 2; ++i)
#pragma unroll
      for (int r = 0; r < 4; ++r) {
        float a = vx_[i][r], b = vf_[i][r];
        a += __shfl_xor(a, 1); a += __shfl_xor(a, 2); a += __shfl_xor(a, 4); a += __shfl_xor(a, 8);
        b += __shfl_xor(b, 1); b += __shfl_xor(b, 2); b += __shfl_xor(b, 4); b += __shfl_xor(b, 8);
        if (cl == 0) {
          const int row = i * 16 + g * 4 + r;
          PX[row * 16 + w] = a;
          PF[row * 16 + w] = b;
        }
      }
  }
  __syncthreads();

  float* ALS = (float*)(smem + 86016);
  if (t < 32) {
    const float* PX = (const float*)(smem + 81920);
    const float* PF = (const float*)(smem + 83968);
    float Vx = 0.f, Vf = 0.f;
#pragma unroll
    for (int i = 0; i < 16; ++i) { Vx += PX[t * 16 + i]; Vf += PF[t * 16 + i]; }
    const float tt2 = 0.99f * Vx;
    float a;
    if (Vf - tt2 > 0.0f)        a = sqrtf(tt2 / Vf);   // Newton limit
    else if (tt2 - Vf > 1e-4f)  a = 0.5f;              // stuck-bisection case
    else                        a = 1.0f;              // never masked
    ALS[t] = a;
  }
  __syncthreads();

  // ---- scaled store (g2 waves own the f values) ----
  if (w >= 8) {
#pragma unroll
    for (int i = 0; i < 2; ++i)
#pragma unroll
      for (int r = 0; r < 4; ++r) {
        const int row = i * 16 + g * 4 + r;
        const float a = ALS[row];
#pragma unroll
        for (int j = 0; j < 2; ++j) {
          const int col = u * 32 + j * 16 + cl;
          OUT[(size_t)(r0 + row) * 256 + col] = oacc[i][j][r] * a;
        }
      }
  }
}

extern "C" void kernel_launch(void* const* d_in, const int* in_sizes, int n_in,
                              void* d_out, int out_size, void* d_ws, size_t ws_size,
                              hipStream_t stream) {
  const float* x  = (const float*)d_in[0];
  const float* W1 = (const float*)d_in[1];
  const float* b1 = (const float*)d_in[2];
  const float* W2 = (const float*)d_in[3];
  const float* b2 = (const float*)d_in[4];
  const float* Wv = (const float*)d_in[5];
  float* out = (float*)d_out;

  char* ws = (char*)d_ws;
  unsigned short* W1Th = (unsigned short*)(ws);
  unsigned short* W1Tl = (unsigned short*)(ws + 524288);
  unsigned short* W2Th = (unsigned short*)(ws + 1048576);
  unsigned short* W2Tl = (unsigned short*)(ws + 1572864);
  unsigned short* WvTh = (unsigned short*)(ws + 2097152);
  unsigned short* WvTl = (unsigned short*)(ws + 2228224);

  k_split<<<dim3(144), dim3(256), 0, stream>>>(W1, W2, Wv, W1Th, W1Tl, W2Th, W2Tl, WvTh, WvTl);
  k_fused<<<dim3(256), dim3(1024), 0, stream>>>(x, b1, b2, W1Th, W1Tl, W2Th, W2Tl, WvTh, WvTl, out);
}

// Round 10
// 83.413 us; speedup vs baseline: 1.4405x; 1.4405x over previous
//
#include <hip/hip_runtime.h>
#include <math.h>

typedef __attribute__((ext_vector_type(8))) short bf16x8;
typedef __attribute__((ext_vector_type(4))) float f32x4;

#define MFMA __builtin_amdgcn_mfma_f32_16x16x32_bf16

static __device__ __forceinline__ unsigned short f2bf(float f) {
  union { float f; unsigned u; } a; a.f = f;
  unsigned u = a.u;
  unsigned r = u + 0x7FFF + ((u >> 16) & 1);   // RNE
  return (unsigned short)(r >> 16);
}
static __device__ __forceinline__ float bf2f(unsigned short h) {
  union { unsigned u; float f; } a; a.u = ((unsigned)h) << 16;
  return a.f;
}
static __device__ __forceinline__ float tanh_fast(float x) {
  float ax = fabsf(x);
  float e = __expf(-2.0f * ax);
  float t = (1.0f - e) / (1.0f + e);
  t = (ax > 10.0f) ? 1.0f : t;
  return (x < 0.0f) ? -t : t;
}
static __device__ __forceinline__ void gload16(const void* g, void* l) {
  __builtin_amdgcn_global_load_lds(
      (const __attribute__((address_space(1))) unsigned int*)g,
      (__attribute__((address_space(3))) unsigned int*)l, 16, 0, 0);
}

// Blocks 0..143: 64x64 LDS-transpose tiles of W1/W2/Wv -> WT hi/lo.
// Blocks 144..1167: elementwise split of x -> Xh/Xl.  (verified r6 code)
__global__ __launch_bounds__(256) void k_split(
    const float* __restrict__ W1, const float* __restrict__ W2,
    const float* __restrict__ Wv, const float* __restrict__ X,
    unsigned short* __restrict__ W1Th, unsigned short* __restrict__ W1Tl,
    unsigned short* __restrict__ W2Th, unsigned short* __restrict__ W2Tl,
    unsigned short* __restrict__ WvTh, unsigned short* __restrict__ WvTl,
    unsigned short* __restrict__ Xh,  unsigned short* __restrict__ Xl)
{
  const int b = blockIdx.x, t = threadIdx.x;
  if (b >= 144) {
    const size_t i0 = (size_t)(b - 144) * 2048 + (size_t)t * 8;
    const float4 v0 = *reinterpret_cast<const float4*>(&X[i0]);
    const float4 v1 = *reinterpret_cast<const float4*>(&X[i0 + 4]);
    const float vv[8] = {v0.x, v0.y, v0.z, v0.w, v1.x, v1.y, v1.z, v1.w};
    uint4 hp, lp;
    unsigned hw[4], lw[4];
#pragma unroll
    for (int e = 0; e < 4; ++e) {
      const unsigned short h0 = f2bf(vv[2*e]), h1 = f2bf(vv[2*e+1]);
      hw[e] = (unsigned)h0 | ((unsigned)h1 << 16);
      lw[e] = (unsigned)f2bf(vv[2*e] - bf2f(h0)) |
              ((unsigned)f2bf(vv[2*e+1] - bf2f(h1)) << 16);
    }
    hp.x = hw[0]; hp.y = hw[1]; hp.z = hw[2]; hp.w = hw[3];
    lp.x = lw[0]; lp.y = lw[1]; lp.z = lw[2]; lp.w = lw[3];
    *reinterpret_cast<uint4*>(&Xh[i0]) = hp;
    *reinterpret_cast<uint4*>(&Xl[i0]) = lp;
    return;
  }

  __shared__ unsigned short shh[64 * 72], shl[64 * 72];
  const float* W; unsigned short *Th, *Tl; int Kd, Nd, k0, n0;
  if (b < 64)       { W = W1; Th = W1Th; Tl = W1Tl; Kd = 256;  Nd = 1024; k0 = (b & 3) * 64;         n0 = (b >> 2) * 64; }
  else if (b < 128) { W = W2; Th = W2Th; Tl = W2Tl; Kd = 1024; Nd = 256;  k0 = ((b - 64) & 15) * 64; n0 = ((b - 64) >> 4) * 64; }
  else              { W = Wv; Th = WvTh; Tl = WvTl; Kd = 256;  Nd = 256;  k0 = ((b - 128) & 3) * 64; n0 = ((b - 128) >> 2) * 64; }

  const int kloc = t >> 4, n4 = t & 15;
#pragma unroll
  for (int p = 0; p < 4; ++p) {
    const int kk = p * 16 + kloc;
    const float4 v = *reinterpret_cast<const float4*>(&W[(size_t)(k0 + kk) * Nd + n0 + n4 * 4]);
    const float vv[4] = {v.x, v.y, v.z, v.w};
#pragma unroll
    for (int e = 0; e < 4; ++e) {
      const unsigned short hh = f2bf(vv[e]);
      shh[(n4 * 4 + e) * 72 + kk] = hh;
      shl[(n4 * 4 + e) * 72 + kk] = f2bf(vv[e] - bf2f(hh));
    }
  }
  __syncthreads();
  const int nl = t >> 2, ko = (t & 3) * 16;
  const size_t dst = (size_t)(n0 + nl) * Kd + k0 + ko;
  *reinterpret_cast<uint4*>(&Th[dst])     = *reinterpret_cast<const uint4*>(&shh[nl * 72 + ko]);
  *reinterpret_cast<uint4*>(&Th[dst + 8]) = *reinterpret_cast<const uint4*>(&shh[nl * 72 + ko + 8]);
  *reinterpret_cast<uint4*>(&Tl[dst])     = *reinterpret_cast<const uint4*>(&shl[nl * 72 + ko]);
  *reinterpret_cast<uint4*>(&Tl[dst + 8]) = *reinterpret_cast<const uint4*>(&shl[nl * 72 + ko + 8]);
}

// GEMM1: H = tanh(x @ W1 + b1).  M=8192 K=256 N=1024.
// m97-faithful: 128x128 tile, BK=32, 4 waves; linear LDS planes [128][32] bf16;
// all staging global_load_lds width-16.  Wave wv stages plane wv.
__global__ __launch_bounds__(256, 3) void k_gemm1(
    const unsigned short* __restrict__ Xh, const unsigned short* __restrict__ Xl,
    const unsigned short* __restrict__ BTh, const unsigned short* __restrict__ BTl,
    const float* __restrict__ bias,
    unsigned short* __restrict__ Hh, unsigned short* __restrict__ Hl)
{
  __shared__ unsigned short lds[16384];  // Ah@0  Al@8192  Bh@16384  Bl@24576 (bytes)
  const int t = threadIdx.x, l = t & 63, wv = t >> 6;
  const int n0 = blockIdx.x * 128, m0 = blockIdx.y * 128;
  const int wr = wv >> 1, wc = wv & 1;

  const unsigned short* ssrc = (wv == 0) ? Xh : (wv == 1) ? Xl : (wv == 2) ? BTh : BTl;
  const int rbase = (wv < 2) ? m0 : n0;
  char* ldsb = (char*)lds + wv * 8192;
  const int srow = l >> 2, sg = l & 3;

  const int kofs = (l >> 4) * 16;   // byte offset of this lane's k-group
  const int arow = wr * 64 + (l & 15), brow = wc * 64 + (l & 15);

  f32x4 acc[4][4] = {};
  for (int k0 = 0; k0 < 256; k0 += 32) {
#pragma unroll
    for (int c = 0; c < 8; ++c)
      gload16(ssrc + (size_t)(rbase + c * 16 + srow) * 256 + k0 + sg * 8, ldsb + c * 1024);
    __syncthreads();

    const char* L = (const char*)lds;
    bf16x8 ah[4], al[4], bh[4], bl[4];
#pragma unroll
    for (int i = 0; i < 4; ++i) {
      ah[i] = *reinterpret_cast<const bf16x8*>(L +         (arow + i * 16) * 64 + kofs);
      al[i] = *reinterpret_cast<const bf16x8*>(L +  8192 + (arow + i * 16) * 64 + kofs);
      bh[i] = *reinterpret_cast<const bf16x8*>(L + 16384 + (brow + i * 16) * 64 + kofs);
      bl[i] = *reinterpret_cast<const bf16x8*>(L + 24576 + (brow + i * 16) * 64 + kofs);
    }
#pragma unroll
    for (int i = 0; i < 4; ++i)
#pragma unroll
      for (int j = 0; j < 4; ++j) {
        acc[i][j] = MFMA(ah[i], bh[j], acc[i][j], 0, 0, 0);
        acc[i][j] = MFMA(ah[i], bl[j], acc[i][j], 0, 0, 0);
        acc[i][j] = MFMA(al[i], bh[j], acc[i][j], 0, 0, 0);
      }
    __syncthreads();
  }

#pragma unroll
  for (int i = 0; i < 4; ++i)
#pragma unroll
    for (int j = 0; j < 4; ++j) {
      const int gn = n0 + wc * 64 + j * 16 + (l & 15);
      const float bv = bias[gn];
#pragma unroll
      for (int r = 0; r < 4; ++r) {
        const int gm = m0 + wr * 64 + i * 16 + (l >> 4) * 4 + r;
        const float tv = tanh_fast(acc[i][j][r] + bv);
        const unsigned short th = f2bf(tv);
        Hh[(size_t)gm * 1024 + gn] = th;
        Hl[(size_t)gm * 1024 + gn] = f2bf(tv - bf2f(th));
      }
    }
}

// Fused gemm2 + V + alpha + scale.  32 rows/block, grid 256, 8 waves.
// out = H @ W2 + b2 + x ; V(x),V(f) via MFMA; alpha; scaled store.
// LDS: XH 16K @0 | XL 16K @16384 | A-dbuf 16K @32768 (buf: Hh 4K + Hl 4K)
//      F planes overlay @32768 (FH 16K) + 49152 (FL 16K) after K-loop
//      PX @65536 1K | PF @66560 1K | ALS @67584 128B   (total 67712B -> 2 blocks/CU)
__global__ __launch_bounds__(512, 4) void k_g2va(
    const unsigned short* __restrict__ Xh, const unsigned short* __restrict__ Xl,
    const unsigned short* __restrict__ Hh, const unsigned short* __restrict__ Hl,
    const unsigned short* __restrict__ W2Th, const unsigned short* __restrict__ W2Tl,
    const unsigned short* __restrict__ WvTh, const unsigned short* __restrict__ WvTl,
    const float* __restrict__ pb2, float* __restrict__ OUT)
{
  __shared__ __align__(16) unsigned char smem[67712];
  const int t = threadIdx.x, l = t & 63, w = t >> 6;
  const int cl = l & 15, g = l >> 4;
  const int r0 = blockIdx.x * 32;

  // ---- prologue: stage X planes (32 gloads) + A chunk 0 (8 gloads) ----
  {
    // X: waves 0-3 -> XH, 4-7 -> XL; 4 gloads each; [32][512B], swz ((row&7)<<4)
    const unsigned short* xp = (w < 4) ? Xh : Xl;
    unsigned char* base = smem + ((w < 4) ? 0 : 16384);
#pragma unroll
    for (int s = 0; s < 4; ++s) {
      const int c = (w & 3) * 4 + s;
      const int row = c * 2 + (l >> 5);
      const int slot = l & 31;
      gload16(xp + (size_t)(r0 + row) * 256 + ((slot ^ (row & 7)) * 8), base + c * 1024);
    }
    // A chunk 0: wave w: plane w>>2 (0=Hh,1=Hl), quarter w&3; [32][128B], swz ((row&7)<<4)
    const unsigned short* hp = (w < 4) ? Hh : Hl;
    unsigned char* abase = smem + 32768 + ((w < 4) ? 0 : 4096) + (w & 3) * 1024;
    const int row = (w & 3) * 8 + (l >> 3);
    const int slot = l & 7;
    gload16(hp + (size_t)(r0 + row) * 1024 + 0 * 64 + ((slot ^ (row & 7)) * 8), abase);
  }
  __syncthreads();

  f32x4 acc[2][2] = {};   // rows {0..15,16..31}, cols w*32 + {0..15,16..31}

  // ---- K-loop: 16 chunks of BK=64 ----
  for (int c = 0; c < 16; ++c) {
    if (c < 15) {
      const int cn = c + 1;
      const unsigned short* hp = (w < 4) ? Hh : Hl;
      unsigned char* abase = smem + 32768 + (cn & 1) * 8192 + ((w < 4) ? 0 : 4096) + (w & 3) * 1024;
      const int row = (w & 3) * 8 + (l >> 3);
      const int slot = l & 7;
      gload16(hp + (size_t)(r0 + row) * 1024 + cn * 64 + ((slot ^ (row & 7)) * 8), abase);
    }
    // B fragments from L2 (issued before dependent ds_reads)
    bf16x8 b2h[2][2], b2l[2][2];
#pragma unroll
    for (int j = 0; j < 2; ++j)
#pragma unroll
      for (int ks = 0; ks < 2; ++ks) {
        const size_t off = (size_t)(w * 32 + j * 16 + cl) * 1024 + c * 64 + ks * 32 + g * 8;
        b2h[j][ks] = *reinterpret_cast<const bf16x8*>(&W2Th[off]);
        b2l[j][ks] = *reinterpret_cast<const bf16x8*>(&W2Tl[off]);
      }
    // A fragments from LDS
    const unsigned char* AB = smem + 32768 + (c & 1) * 8192;
    bf16x8 a2h[2][2], a2l[2][2];
#pragma unroll
    for (int i = 0; i < 2; ++i)
#pragma unroll
      for (int ks = 0; ks < 2; ++ks) {
        const int row = i * 16 + cl;
        const unsigned byte = row * 128 + (((unsigned)(ks * 64 + g * 16)) ^ ((((unsigned)row) & 7u) << 4));
        a2h[i][ks] = *reinterpret_cast<const bf16x8*>(AB + byte);
        a2l[i][ks] = *reinterpret_cast<const bf16x8*>(AB + 4096 + byte);
      }
#pragma unroll
    for (int i = 0; i < 2; ++i)
#pragma unroll
      for (int j = 0; j < 2; ++j)
#pragma unroll
        for (int ks = 0; ks < 2; ++ks) {
          acc[i][j] = MFMA(a2h[i][ks], b2h[j][ks], acc[i][j], 0, 0, 0);
          acc[i][j] = MFMA(a2h[i][ks], b2l[j][ks], acc[i][j], 0, 0, 0);
          acc[i][j] = MFMA(a2l[i][ks], b2h[j][ks], acc[i][j], 0, 0, 0);
        }
    __syncthreads();
  }

  // ---- epilogue: f = acc + b2 + x ; write F planes (overlay A-dbuf) ----
  {
    float b2v[2];
#pragma unroll
    for (int j = 0; j < 2; ++j) b2v[j] = pb2[w * 32 + j * 16 + cl];
#pragma unroll
    for (int i = 0; i < 2; ++i)
#pragma unroll
      for (int j = 0; j < 2; ++j)
#pragma unroll
        for (int r = 0; r < 4; ++r) {
          const int row = i * 16 + g * 4 + r;
          const int col = w * 32 + j * 16 + cl;
          const unsigned xb = row * 512 + (((unsigned)(col * 2)) ^ ((((unsigned)row) & 7u) << 4));
          const float xv = bf2f(*reinterpret_cast<unsigned short*>(smem + xb)) +
                           bf2f(*reinterpret_cast<unsigned short*>(smem + 16384 + xb));
          const float f = acc[i][j][r] + b2v[j] + xv;
          acc[i][j][r] = f;
          const unsigned short fh = f2bf(f);
          *reinterpret_cast<unsigned short*>(smem + 32768 + xb) = fh;
          *reinterpret_cast<unsigned short*>(smem + 49152 + xb) = f2bf(f - bf2f(fh));
        }
  }
  __syncthreads();

  // ---- V phase: wave owns 32 Wv cols; Wv frags from L2 (loaded once) ----
  {
    float vx_[2][4] = {}, vf_[2][4] = {};
    f32x4 zx[2], zf[2];
#pragma unroll
    for (int nf = 0; nf < 2; ++nf) {
      zx[0] = (f32x4){}; zx[1] = (f32x4){};
      zf[0] = (f32x4){}; zf[1] = (f32x4){};
#pragma unroll
      for (int ks = 0; ks < 8; ++ks) {
        const size_t off = (size_t)(w * 32 + nf * 16 + cl) * 256 + ks * 32 + g * 8;
        const bf16x8 wvh = *reinterpret_cast<const bf16x8*>(&WvTh[off]);
        const bf16x8 wvl = *reinterpret_cast<const bf16x8*>(&WvTl[off]);
#pragma unroll
        for (int i = 0; i < 2; ++i) {
          const int row = i * 16 + cl;
          const unsigned o = ((unsigned)(ks * 64 + g * 16)) ^ ((((unsigned)row) & 7u) << 4);
          const bf16x8 xhv = *reinterpret_cast<const bf16x8*>(smem + row * 512 + o);
          const bf16x8 xlv = *reinterpret_cast<const bf16x8*>(smem + 16384 + row * 512 + o);
          const bf16x8 fhv = *reinterpret_cast<const bf16x8*>(smem + 32768 + row * 512 + o);
          const bf16x8 flv = *reinterpret_cast<const bf16x8*>(smem + 49152 + row * 512 + o);
          zx[i] = MFMA(xhv, wvh, zx[i], 0, 0, 0);
          zx[i] = MFMA(xhv, wvl, zx[i], 0, 0, 0);
          zx[i] = MFMA(xlv, wvh, zx[i], 0, 0, 0);
          zf[i] = MFMA(fhv, wvh, zf[i], 0, 0, 0);
          zf[i] = MFMA(fhv, wvl, zf[i], 0, 0, 0);
          zf[i] = MFMA(flv, wvh, zf[i], 0, 0, 0);
        }
      }
#pragma unroll
      for (int i = 0; i < 2; ++i)
#pragma unroll
        for (int r = 0; r < 4; ++r) {
          vx_[i][r] = fmaf(zx[i][r], zx[i][r], vx_[i][r]);
          vf_[i][r] = fmaf(zf[i][r], zf[i][r], vf_[i][r]);
        }
    }
    float* PX = (float*)(smem + 65536);
    float* PF = (float*)(smem + 66560);
#pragma unroll
    for (int i = 0; i < 2; ++i)
#pragma unroll
      for (int r = 0; r < 4; ++r) {
        float a = vx_[i][r], b = vf_[i][r];
        a += __shfl_xor(a, 1); a += __shfl_xor(a, 2); a += __shfl_xor(a, 4); a += __shfl_xor(a, 8);
        b += __shfl_xor(b, 1); b += __shfl_xor(b, 2); b += __shfl_xor(b, 4); b += __shfl_xor(b, 8);
        if (cl == 0) {
          const int row = i * 16 + g * 4 + r;
          PX[row * 8 + w] = a;
          PF[row * 8 + w] = b;
        }
      }
  }
  __syncthreads();

  float* ALS = (float*)(smem + 67584);
  if (t < 32) {
    const float* PX = (const float*)(smem + 65536);
    const float* PF = (const float*)(smem + 66560);
    float Vx = 0.f, Vf = 0.f;
#pragma unroll
    for (int i = 0; i < 8; ++i) { Vx += PX[t * 8 + i]; Vf += PF[t * 8 + i]; }
    const float tt2 = 0.99f * Vx;
    float a;
    if (Vf - tt2 > 0.0f)        a = sqrtf(tt2 / Vf);   // Newton limit
    else if (tt2 - Vf > 1e-4f)  a = 0.5f;              // stuck-bisection case
    else                        a = 1.0f;              // never masked
    ALS[t] = a;
  }
  __syncthreads();

#pragma unroll
  for (int i = 0; i < 2; ++i)
#pragma unroll
    for (int r = 0; r < 4; ++r) {
      const int row = i * 16 + g * 4 + r;
      const float a = ALS[row];
#pragma unroll
      for (int j = 0; j < 2; ++j) {
        const int col = w * 32 + j * 16 + cl;
        OUT[(size_t)(r0 + row) * 256 + col] = acc[i][j][r] * a;
      }
    }
}

extern "C" void kernel_launch(void* const* d_in, const int* in_sizes, int n_in,
                              void* d_out, int out_size, void* d_ws, size_t ws_size,
                              hipStream_t stream) {
  const float* x  = (const float*)d_in[0];
  const float* W1 = (const float*)d_in[1];
  const float* b1 = (const float*)d_in[2];
  const float* W2 = (const float*)d_in[3];
  const float* b2 = (const float*)d_in[4];
  const float* Wv = (const float*)d_in[5];
  float* out = (float*)d_out;

  char* ws = (char*)d_ws;
  unsigned short* Hh   = (unsigned short*)(ws);                    // 16.8 MB
  unsigned short* Hl   = (unsigned short*)(ws + 16777216);         // 16.8 MB
  unsigned short* W1Th = (unsigned short*)(ws + 33554432);
  unsigned short* W1Tl = (unsigned short*)(ws + 34078720);
  unsigned short* W2Th = (unsigned short*)(ws + 34603008);
  unsigned short* W2Tl = (unsigned short*)(ws + 35127296);
  unsigned short* WvTh = (unsigned short*)(ws + 35651584);
  unsigned short* WvTl = (unsigned short*)(ws + 35782656);
  unsigned short* Xh   = (unsigned short*)(ws + 35913728);         // 4.2 MB
  unsigned short* Xl   = (unsigned short*)(ws + 40108032);         // 4.2 MB

  k_split<<<dim3(1168), dim3(256), 0, stream>>>(
      W1, W2, Wv, x, W1Th, W1Tl, W2Th, W2Tl, WvTh, WvTl, Xh, Xl);

  k_gemm1<<<dim3(8, 64), dim3(256), 0, stream>>>(Xh, Xl, W1Th, W1Tl, b1, Hh, Hl);
  k_g2va <<<dim3(256), dim3(512), 0, stream>>>(Xh, Xl, Hh, Hl, W2Th, W2Tl, WvTh, WvTl, b2, out);
}